// Round 1
// baseline (419.147 us; speedup 1.0000x reference)
//
#include <hip/hip_runtime.h>
#include <math.h>

#define LSEQ 4096
#define MFFT 8192
#define NM   64
#define NBH  4096
#define TMAIN 512

__device__ __forceinline__ float2 cmulf(float2 a, float2 b) {
  return make_float2(a.x*b.x - a.y*b.y, a.x*b.y + a.y*b.x);
}
__device__ __forceinline__ float2 caddf(float2 a, float2 b){ return make_float2(a.x+b.x, a.y+b.y); }
__device__ __forceinline__ float2 csubf(float2 a, float2 b){ return make_float2(a.x-b.x, a.y-b.y); }

// ---------------- prep: twiddle table W_M^t = exp(-2*pi*i*t/M), t in [0, M/4) ----------------
__global__ void twiddle_kernel(float2* __restrict__ tw) {
  int t = blockIdx.x*blockDim.x + threadIdx.x;
  if (t < MFFT/4) {
    double ang = -2.0*M_PI*(double)t/(double)MFFT;
    tw[t] = make_float2((float)cos(ang), (float)sin(ang));
  }
}

// ---------------- prep: at_roots[k] via 4 Cauchy dots (double precision) ----------------
__global__ void cauchy_kernel(const float* __restrict__ Lre, const float* __restrict__ Lim,
                              const float* __restrict__ Pre, const float* __restrict__ Pim,
                              const float* __restrict__ Bre, const float* __restrict__ Bim,
                              const float* __restrict__ Cri, const float* __restrict__ lstep,
                              float2* __restrict__ a_out) {
  int k = blockIdx.x*blockDim.x + threadIdx.x;
  if (k >= LSEQ) return;
  double step = exp((double)lstep[0]);
  double ang = -2.0*M_PI*(double)k/(double)LSEQ;
  double wr = cos(ang), wi = sin(ang);
  // n = 1-Omega, d = 1+Omega
  double nr = 1.0 - wr, ni = -wi;
  double dr = 1.0 + wr, di = wi;
  double dn = dr*dr + di*di;            // |1+Omega|^2 (never exactly 0 in fp: sin(pi_f64)!=0)
  double gre = (2.0/step) * (nr*dr + ni*di)/dn;
  double gim = (2.0/step) * (ni*dr - nr*di)/dn;
  double cre = 2.0*dr/dn, cim = -2.0*di/dn;   // c = 2/(1+Omega)
  double k00r=0,k00i=0,k01r=0,k01i=0,k10r=0,k10i=0,k11r=0,k11i=0;
  for (int n = 0; n < NM; n++) {
    double lre = Lre[n], lim = Lim[n];
    double pre = Pre[n], pim = Pim[n];
    double bre = Bre[n], bim = Bim[n];
    double ccr = Cri[2*n], cci = Cri[2*n+1];
    // 1/(g - Lambda)
    double er = gre - lre, ei = gim - lim;
    double inv = 1.0/(er*er + ei*ei);
    double ir =  er*inv, ii = -ei*inv;
    // v00 = conj(C)*B, v01 = conj(C)*P, v10 = conj(P)*B, v11 = conj(P)*P
    double v00r = ccr*bre + cci*bim, v00i = ccr*bim - cci*bre;
    double v01r = ccr*pre + cci*pim, v01i = ccr*pim - cci*pre;
    double v10r = pre*bre + pim*bim, v10i = pre*bim - pim*bre;
    double v11r = pre*pre + pim*pim, v11i = 0.0;
    k00r += v00r*ir - v00i*ii;  k00i += v00r*ii + v00i*ir;
    k01r += v01r*ir - v01i*ii;  k01i += v01r*ii + v01i*ir;
    k10r += v10r*ir - v10i*ii;  k10i += v10r*ii + v10i*ir;
    k11r += v11r*ir - v11i*ii;  k11i += v11r*ii + v11i*ir;
  }
  // q = k01*k10/(1+k11); a = c*(k00 - q)
  double numr = k01r*k10r - k01i*k10i, numi = k01r*k10i + k01i*k10r;
  double der = 1.0 + k11r, dei = k11i;
  double dinv = 1.0/(der*der + dei*dei);
  double qr = (numr*der + numi*dei)*dinv;
  double qi = (numi*der - numr*dei)*dinv;
  double tr = k00r - qr, ti = k00i - qi;
  double ar = cre*tr - cim*ti, ai = cre*ti + cim*tr;
  a_out[k] = make_float2((float)ar, (float)ai);
}

// ---------------- prep: K[l] = Re(IDFT_L(a))[l]  (direct sum, incremental double twiddle) ----
__global__ void ktime_kernel(const float2* __restrict__ a, float* __restrict__ K) {
  int l = blockIdx.x*blockDim.x + threadIdx.x;
  if (l >= LSEQ) return;
  double ang = 2.0*M_PI*(double)l/(double)LSEQ;
  double wr = cos(ang), wi = sin(ang);
  double tr = 1.0, ti = 0.0;
  double acc = 0.0;
  for (int k = 0; k < LSEQ; k++) {
    float2 ak = a[k];
    acc += (double)ak.x*tr - (double)ak.y*ti;   // Re(a[k] * e^{+2pi i k l/L})
    double ntr = tr*wr - ti*wi;
    ti = tr*wi + ti*wr;
    tr = ntr;
  }
  K[l] = (float)(acc/(double)LSEQ);
}

// ---------------- shared FFT stages: DIF radix-4 x6 + radix-2 (scrambled out) ----------------
template<int T>
__device__ void fft_fwd(float2* __restrict__ z, const float2* __restrict__ tw, int tid) {
  #pragma unroll
  for (int s = MFFT/4; s >= 2; s >>= 2) {
    const int m = MFFT/(4*s);
    #pragma unroll
    for (int bb = 0; bb < MFFT/4; bb += T) {
      int b = bb + tid;
      int j = b & (s-1);
      int base = ((b & ~(s-1)) << 2) | j;
      float2 x0 = z[base], x1 = z[base+s], x2 = z[base+2*s], x3 = z[base+3*s];
      float2 A  = caddf(x0,x2), C = csubf(x0,x2);
      float2 Bv = caddf(x1,x3), D = csubf(x1,x3);
      int e1 = j*m, e2 = e1+e1;
      float2 w1 = tw[e1];
      float2 w2;
      if (e2 < MFFT/4) w2 = tw[e2];
      else { float2 t2 = tw[e2 - MFFT/4]; w2 = make_float2(t2.y, -t2.x); }  // -i * t
      float2 w3 = cmulf(w1, w2);
      float2 y1 = make_float2(C.x + D.y, C.y - D.x);   // C - iD
      float2 y3 = make_float2(C.x - D.y, C.y + D.x);   // C + iD
      z[base]      = caddf(A, Bv);
      z[base+s]    = cmulf(y1, w1);
      z[base+2*s]  = cmulf(csubf(A, Bv), w2);
      z[base+3*s]  = cmulf(y3, w3);
    }
    __syncthreads();
  }
  #pragma unroll
  for (int bb = 0; bb < MFFT/2; bb += T) {
    int b = bb + tid;
    float2 x0 = z[2*b], x1 = z[2*b+1];
    z[2*b]   = caddf(x0,x1);
    z[2*b+1] = csubf(x0,x1);
  }
  __syncthreads();
}

template<int T>
__device__ void fft_inv(float2* __restrict__ z, const float2* __restrict__ tw, int tid) {
  #pragma unroll
  for (int bb = 0; bb < MFFT/2; bb += T) {
    int b = bb + tid;
    float2 x0 = z[2*b], x1 = z[2*b+1];
    z[2*b]   = caddf(x0,x1);
    z[2*b+1] = csubf(x0,x1);
  }
  __syncthreads();
  #pragma unroll
  for (int s = 2; s <= MFFT/4; s <<= 2) {
    const int m = MFFT/(4*s);
    #pragma unroll
    for (int bb = 0; bb < MFFT/4; bb += T) {
      int b = bb + tid;
      int j = b & (s-1);
      int base = ((b & ~(s-1)) << 2) | j;
      float2 y0 = z[base], y1 = z[base+s], y2 = z[base+2*s], y3 = z[base+3*s];
      int e1 = j*m, e2 = e1+e1;
      float2 w1 = tw[e1]; w1 = make_float2(w1.x, -w1.y);                     // conj
      float2 w2c;
      if (e2 < MFFT/4) { float2 t2 = tw[e2]; w2c = make_float2(t2.x, -t2.y); }
      else { float2 t2 = tw[e2 - MFFT/4]; w2c = make_float2(t2.y, t2.x); }   // conj(-i t)
      float2 w3c = cmulf(w1, w2c);
      float2 c1 = cmulf(y1, w1);
      float2 c2 = cmulf(y2, w2c);
      float2 c3 = cmulf(y3, w3c);
      float2 ap = caddf(y0, c2), bp = csubf(y0, c2);
      float2 cp = caddf(c1, c3);
      float2 dp = make_float2(c3.y - c1.y, c1.x - c3.x);                     // i*(c1-c3)
      z[base]      = caddf(ap, cp);
      z[base+s]    = caddf(bp, dp);
      z[base+2*s]  = csubf(ap, cp);
      z[base+3*s]  = csubf(bp, dp);
    }
    __syncthreads();
  }
}

// ---------------- prep: Kd = fwd_fft(pad(K)) / M, in the same scrambled order ---------------
__global__ void kd_kernel(const float* __restrict__ K, const float2* __restrict__ twg,
                          float2* __restrict__ Kd) {
  __shared__ float2 z[MFFT];
  __shared__ float2 twl[MFFT/4];
  int tid = threadIdx.x;
  for (int i = tid; i < MFFT/4; i += TMAIN) twl[i] = twg[i];
  for (int i = tid; i < MFFT; i += TMAIN)
    z[i] = make_float2(i < LSEQ ? K[i] : 0.0f, 0.0f);
  __syncthreads();
  fft_fwd<TMAIN>(z, twl, tid);
  const float sc = 1.0f/(float)MFFT;
  for (int i = tid; i < MFFT; i += TMAIN)
    Kd[i] = make_float2(z[i].x*sc, z[i].y*sc);
}

// ---------------- main: 2 rows per block packed as one complex signal ----------------
__global__ __launch_bounds__(TMAIN, 4)
void conv_kernel(const float* __restrict__ u, const float* __restrict__ Dp,
                 const float2* __restrict__ twg, const float2* __restrict__ Kd,
                 float* __restrict__ out) {
  __shared__ float2 z[MFFT];
  __shared__ float2 twl[MFFT/4];
  int tid = threadIdx.x;
  int r0 = blockIdx.x, r1 = blockIdx.x + (NBH/2);
  const float4* u0 = (const float4*)(u + (size_t)r0*LSEQ);
  const float4* u1 = (const float4*)(u + (size_t)r1*LSEQ);
  for (int i = tid; i < MFFT/4; i += TMAIN) twl[i] = twg[i];
  float4 a0[2], a1[2];
  #pragma unroll
  for (int q = 0; q < 2; q++) {
    int idx = tid + TMAIN*q;                 // float4 index, < 1024
    a0[q] = u0[idx]; a1[q] = u1[idx];
    z[4*idx+0] = make_float2(a0[q].x, a1[q].x);
    z[4*idx+1] = make_float2(a0[q].y, a1[q].y);
    z[4*idx+2] = make_float2(a0[q].z, a1[q].z);
    z[4*idx+3] = make_float2(a0[q].w, a1[q].w);
  }
  for (int i = tid + LSEQ; i < MFFT; i += TMAIN) z[i] = make_float2(0.f, 0.f);
  __syncthreads();
  fft_fwd<TMAIN>(z, twl, tid);
  #pragma unroll
  for (int p0 = 0; p0 < MFFT; p0 += TMAIN) {
    int p = p0 + tid;
    z[p] = cmulf(z[p], Kd[p]);
  }
  __syncthreads();
  fft_inv<TMAIN>(z, twl, tid);
  const float Dv = Dp[0];
  float* o0 = out + (size_t)r0*LSEQ;
  float* o1 = out + (size_t)r1*LSEQ;
  #pragma unroll
  for (int q = 0; q < 2; q++) {
    int idx = tid + TMAIN*q;
    float2 w0 = z[4*idx+0], w1 = z[4*idx+1], w2 = z[4*idx+2], w3 = z[4*idx+3];
    float4 y0, y1;
    y0.x = w0.x + Dv*a0[q].x;  y1.x = w0.y + Dv*a1[q].x;
    y0.y = w1.x + Dv*a0[q].y;  y1.y = w1.y + Dv*a1[q].y;
    y0.z = w2.x + Dv*a0[q].z;  y1.z = w2.y + Dv*a1[q].z;
    y0.w = w3.x + Dv*a0[q].w;  y1.w = w3.y + Dv*a1[q].w;
    ((float4*)o0)[idx] = y0;
    ((float4*)o1)[idx] = y1;
  }
}

extern "C" void kernel_launch(void* const* d_in, const int* in_sizes, int n_in,
                              void* d_out, int out_size, void* d_ws, size_t ws_size,
                              hipStream_t stream) {
  const float* u     = (const float*)d_in[0];
  const float* Lre   = (const float*)d_in[1];
  const float* Lim   = (const float*)d_in[2];
  const float* Pre   = (const float*)d_in[3];
  const float* Pim   = (const float*)d_in[4];
  const float* Bre   = (const float*)d_in[5];
  const float* Bim   = (const float*)d_in[6];
  const float* Cri   = (const float*)d_in[7];
  const float* Dp    = (const float*)d_in[8];
  const float* lstep = (const float*)d_in[9];
  float* out = (float*)d_out;

  char* ws = (char*)d_ws;
  float2* a_ws  = (float2*)(ws);                  //  32768 B : at_roots (4096 c64->c32)
  float*  K_ws  = (float*)(ws + 32768);           //  16384 B : K time domain
  float2* Kd_ws = (float2*)(ws + 49152);          //  65536 B : Kd (scrambled, /M)
  float2* tw_ws = (float2*)(ws + 114688);         //  16384 B : twiddles  (total 128 KB)

  hipLaunchKernelGGL(twiddle_kernel, dim3(8),   dim3(256), 0, stream, tw_ws);
  hipLaunchKernelGGL(cauchy_kernel,  dim3(16),  dim3(256), 0, stream,
                     Lre, Lim, Pre, Pim, Bre, Bim, Cri, lstep, a_ws);
  hipLaunchKernelGGL(ktime_kernel,   dim3(16),  dim3(256), 0, stream, a_ws, K_ws);
  hipLaunchKernelGGL(kd_kernel,      dim3(1),   dim3(TMAIN), 0, stream, K_ws, tw_ws, Kd_ws);
  hipLaunchKernelGGL(conv_kernel,    dim3(NBH/2), dim3(TMAIN), 0, stream,
                     u, Dp, tw_ws, Kd_ws, out);
}

// Round 2
// 149.091 us; speedup vs baseline: 2.8113x; 2.8113x over previous
//
#include <hip/hip_runtime.h>
#include <math.h>

#define LSEQ 4096
#define MFFT 8192
#define NM   64
#define NBH  4096
#define TMAIN 512
#define TWQ_N  1088   // quarter twiddle table, entries 0..1024 used
#define CTAB_N 682    // per-stage compact tables: s=512,128,32,8,2

__device__ __forceinline__ float2 cmulf(float2 a, float2 b) {
  return make_float2(a.x*b.x - a.y*b.y, a.x*b.y + a.y*b.x);
}
__device__ __forceinline__ float2 caddf(float2 a, float2 b){ return make_float2(a.x+b.x, a.y+b.y); }
__device__ __forceinline__ float2 csubf(float2 a, float2 b){ return make_float2(a.x-b.x, a.y-b.y); }

// storage swizzle: permute within each 16-element (128B) block -> small-stride
// stages drop from 16-way to 4-way (floor) conflicts; contiguous stays minimal
__device__ __forceinline__ int ZS(int i){ return i ^ ((i >> 4) & 15); }

__host__ __device__ constexpr int coff(int s){
  return s==512 ? 0 : s==128 ? 512 : s==32 ? 640 : s==8 ? 672 : 680;
}

// ---------------- prep: twiddle tables (double -> float) ----------------
__global__ void tables_kernel(float2* __restrict__ twq, float2* __restrict__ ctab) {
  int t = blockIdx.x*blockDim.x + threadIdx.x;
  if (t < TWQ_N) {
    double ang = -2.0*M_PI*(double)t/(double)MFFT;
    twq[t] = make_float2((float)cos(ang), (float)sin(ang));
  }
  int u = t - TWQ_N;
  if (u >= 0 && u < CTAB_N) {
    int s, j;
    if      (u < 512){ s=512; j=u; }
    else if (u < 640){ s=128; j=u-512; }
    else if (u < 672){ s=32;  j=u-640; }
    else if (u < 680){ s=8;   j=u-672; }
    else             { s=2;   j=u-680; }
    double ang = -2.0*M_PI*(double)j/(double)(4*s);
    ctab[u] = make_float2((float)cos(ang), (float)sin(ang));
  }
}

// ---------------- prep: at_roots[k] via 4 Cauchy dots (double precision) ----------------
__global__ void cauchy_kernel(const float* __restrict__ Lre, const float* __restrict__ Lim,
                              const float* __restrict__ Pre, const float* __restrict__ Pim,
                              const float* __restrict__ Bre, const float* __restrict__ Bim,
                              const float* __restrict__ Cri, const float* __restrict__ lstep,
                              float2* __restrict__ a_out) {
  int k = blockIdx.x*blockDim.x + threadIdx.x;
  if (k >= LSEQ) return;
  double step = exp((double)lstep[0]);
  double ang = -2.0*M_PI*(double)k/(double)LSEQ;
  double wr = cos(ang), wi = sin(ang);
  double nr = 1.0 - wr, ni = -wi;
  double dr = 1.0 + wr, di = wi;
  double dn = dr*dr + di*di;
  double gre = (2.0/step) * (nr*dr + ni*di)/dn;
  double gim = (2.0/step) * (ni*dr - nr*di)/dn;
  double cre = 2.0*dr/dn, cim = -2.0*di/dn;
  double k00r=0,k00i=0,k01r=0,k01i=0,k10r=0,k10i=0,k11r=0,k11i=0;
  for (int n = 0; n < NM; n++) {
    double lre = Lre[n], lim = Lim[n];
    double pre = Pre[n], pim = Pim[n];
    double bre = Bre[n], bim = Bim[n];
    double ccr = Cri[2*n], cci = Cri[2*n+1];
    double er = gre - lre, ei = gim - lim;
    double inv = 1.0/(er*er + ei*ei);
    double ir =  er*inv, ii = -ei*inv;
    double v00r = ccr*bre + cci*bim, v00i = ccr*bim - cci*bre;
    double v01r = ccr*pre + cci*pim, v01i = ccr*pim - cci*pre;
    double v10r = pre*bre + pim*bim, v10i = pre*bim - pim*bre;
    double v11r = pre*pre + pim*pim, v11i = 0.0;
    k00r += v00r*ir - v00i*ii;  k00i += v00r*ii + v00i*ir;
    k01r += v01r*ir - v01i*ii;  k01i += v01r*ii + v01i*ir;
    k10r += v10r*ir - v10i*ii;  k10i += v10r*ii + v10i*ir;
    k11r += v11r*ir - v11i*ii;  k11i += v11r*ii + v11i*ir;
  }
  double numr = k01r*k10r - k01i*k10i, numi = k01r*k10i + k01i*k10r;
  double der = 1.0 + k11r, dei = k11i;
  double dinv = 1.0/(der*der + dei*dei);
  double qr = (numr*der + numi*dei)*dinv;
  double qi = (numi*der - numr*dei)*dinv;
  double tr = k00r - qr, ti = k00i - qi;
  double ar = cre*tr - cim*ti, ai = cre*ti + cim*tr;
  a_out[k] = make_float2((float)ar, (float)ai);
}

// ---------------- prep: K[l] = Re(IDFT_L(a))[l], 64 lanes per output ----------------
__global__ void ktime_kernel(const float2* __restrict__ a, float* __restrict__ K) {
  int lane = threadIdx.x & 63;
  int l = blockIdx.x * (blockDim.x >> 6) + (threadIdx.x >> 6);
  if (l >= LSEQ) return;
  // e^{+2pi i l (lane + 64k)/L}: start at lane, step by 64
  double ang0 = 2.0*M_PI*(double)((l*lane) & (LSEQ-1))/(double)LSEQ;
  double tr = cos(ang0), ti = sin(ang0);
  double ang1 = 2.0*M_PI*(double)(l & 63)/64.0;
  double wr = cos(ang1), wi = sin(ang1);
  double acc = 0.0;
  for (int k = 0; k < 64; k++) {
    float2 ak = a[lane + (k << 6)];
    acc += (double)ak.x*tr - (double)ak.y*ti;
    double ntr = tr*wr - ti*wi;
    ti = tr*wi + ti*wr;
    tr = ntr;
  }
  for (int off = 32; off > 0; off >>= 1) acc += __shfl_down(acc, off);
  if (lane == 0) K[l] = (float)(acc/(double)LSEQ);
}

// ---------------- twiddle fetch for stage s, index j (compile-time s) ----------------
template<int S>
__device__ __forceinline__ float2 get_w1(const float2* __restrict__ twq,
                                         const float2* __restrict__ ctab, int j) {
  if (S == MFFT/4) {
    int sel = (j <= MFFT/8);
    int jj = sel ? j : (MFFT/4 - j);
    float2 t = twq[jj];
    return sel ? t : make_float2(-t.y, -t.x);   // e^{-2pi i j/M} via quarter fold
  } else {
    return ctab[coff(S) + j];
  }
}

// ---------------- shared FFT stages: DIF radix-4 x6 + radix-2 (scrambled out) ----------------
template<int T, int S>
__device__ __forceinline__ void fwd_stage(float2* __restrict__ z, const float2* __restrict__ twq,
                                          const float2* __restrict__ ctab, int tid) {
  #pragma unroll
  for (int bb = 0; bb < MFFT/4; bb += T) {
    int b = bb + tid;
    int j = b & (S-1);
    int base = ((b & ~(S-1)) << 2) | j;
    int i0 = ZS(base), i1 = ZS(base+S), i2 = ZS(base+2*S), i3 = ZS(base+3*S);
    float2 x0 = z[i0], x1 = z[i1], x2 = z[i2], x3 = z[i3];
    float2 A  = caddf(x0,x2), C = csubf(x0,x2);
    float2 Bv = caddf(x1,x3), D = csubf(x1,x3);
    float2 w1 = get_w1<S>(twq, ctab, j);
    float2 w2 = cmulf(w1, w1);
    float2 w3 = cmulf(w1, w2);
    float2 y1 = make_float2(C.x + D.y, C.y - D.x);   // C - iD
    float2 y3 = make_float2(C.x - D.y, C.y + D.x);   // C + iD
    z[i0] = caddf(A, Bv);
    z[i1] = cmulf(y1, w1);
    z[i2] = cmulf(csubf(A, Bv), w2);
    z[i3] = cmulf(y3, w3);
  }
  __syncthreads();
}

template<int T, int S>
__device__ __forceinline__ void inv_stage(float2* __restrict__ z, const float2* __restrict__ twq,
                                          const float2* __restrict__ ctab, int tid) {
  #pragma unroll
  for (int bb = 0; bb < MFFT/4; bb += T) {
    int b = bb + tid;
    int j = b & (S-1);
    int base = ((b & ~(S-1)) << 2) | j;
    int i0 = ZS(base), i1 = ZS(base+S), i2 = ZS(base+2*S), i3 = ZS(base+3*S);
    float2 y0 = z[i0], y1 = z[i1], y2 = z[i2], y3 = z[i3];
    float2 w1 = get_w1<S>(twq, ctab, j);
    float2 w1c = make_float2(w1.x, -w1.y);
    float2 w2c = cmulf(w1c, w1c);
    float2 w3c = cmulf(w1c, w2c);
    float2 c1 = cmulf(y1, w1c);
    float2 c2 = cmulf(y2, w2c);
    float2 c3 = cmulf(y3, w3c);
    float2 ap = caddf(y0, c2), bp = csubf(y0, c2);
    float2 cp = caddf(c1, c3);
    float2 dp = make_float2(c3.y - c1.y, c1.x - c3.x);  // i*(c1-c3)
    z[i0] = caddf(ap, cp);
    z[i1] = caddf(bp, dp);
    z[i2] = csubf(ap, cp);
    z[i3] = csubf(bp, dp);
  }
  __syncthreads();
}

template<int T>
__device__ void fft_fwd(float2* __restrict__ z, const float2* __restrict__ twq,
                        const float2* __restrict__ ctab, int tid) {
  fwd_stage<T, 2048>(z, twq, ctab, tid);
  fwd_stage<T, 512 >(z, twq, ctab, tid);
  fwd_stage<T, 128 >(z, twq, ctab, tid);
  fwd_stage<T, 32  >(z, twq, ctab, tid);
  fwd_stage<T, 8   >(z, twq, ctab, tid);
  fwd_stage<T, 2   >(z, twq, ctab, tid);
  #pragma unroll
  for (int bb = 0; bb < MFFT/2; bb += T) {
    int b = bb + tid;
    int i0 = ZS(2*b), i1 = ZS(2*b+1);
    float2 x0 = z[i0], x1 = z[i1];
    z[i0] = caddf(x0,x1);
    z[i1] = csubf(x0,x1);
  }
  __syncthreads();
}

template<int T>
__device__ void fft_inv(float2* __restrict__ z, const float2* __restrict__ twq,
                        const float2* __restrict__ ctab, int tid) {
  #pragma unroll
  for (int bb = 0; bb < MFFT/2; bb += T) {
    int b = bb + tid;
    int i0 = ZS(2*b), i1 = ZS(2*b+1);
    float2 x0 = z[i0], x1 = z[i1];
    z[i0] = caddf(x0,x1);
    z[i1] = csubf(x0,x1);
  }
  __syncthreads();
  inv_stage<T, 2   >(z, twq, ctab, tid);
  inv_stage<T, 8   >(z, twq, ctab, tid);
  inv_stage<T, 32  >(z, twq, ctab, tid);
  inv_stage<T, 128 >(z, twq, ctab, tid);
  inv_stage<T, 512 >(z, twq, ctab, tid);
  inv_stage<T, 2048>(z, twq, ctab, tid);
}

// ---------------- prep: Kd = fwd_fft(pad(K)) / M, stored in PHYSICAL order ---------------
__global__ void kd_kernel(const float* __restrict__ K, const float2* __restrict__ twq_g,
                          const float2* __restrict__ ctab_g, float2* __restrict__ Kd) {
  __shared__ float2 z[MFFT];
  __shared__ float2 twl[TWQ_N];
  __shared__ float2 ctl[CTAB_N];
  int tid = threadIdx.x;
  for (int i = tid; i < TWQ_N;  i += TMAIN) twl[i] = twq_g[i];
  for (int i = tid; i < CTAB_N; i += TMAIN) ctl[i] = ctab_g[i];
  for (int i = tid; i < MFFT; i += TMAIN)
    z[ZS(i)] = make_float2(i < LSEQ ? K[i] : 0.0f, 0.0f);
  __syncthreads();
  fft_fwd<TMAIN>(z, twl, ctl, tid);
  const float sc = 1.0f/(float)MFFT;
  for (int i = tid; i < MFFT; i += TMAIN)
    Kd[i] = make_float2(z[i].x*sc, z[i].y*sc);   // physical order
}

// ---------------- main: 2 rows per block packed as one complex signal ----------------
__global__ __launch_bounds__(TMAIN, 4)
void conv_kernel(const float* __restrict__ u, const float* __restrict__ Dp,
                 const float2* __restrict__ twq_g, const float2* __restrict__ ctab_g,
                 const float2* __restrict__ Kd, float* __restrict__ out) {
  __shared__ float2 z[MFFT];
  __shared__ float2 twl[TWQ_N];
  __shared__ float2 ctl[CTAB_N];
  int tid = threadIdx.x;
  int r0 = blockIdx.x, r1 = blockIdx.x + (NBH/2);
  const float4* u0 = (const float4*)(u + (size_t)r0*LSEQ);
  const float4* u1 = (const float4*)(u + (size_t)r1*LSEQ);
  for (int i = tid; i < TWQ_N;  i += TMAIN) twl[i] = twq_g[i];
  for (int i = tid; i < CTAB_N; i += TMAIN) ctl[i] = ctab_g[i];
  float4 a0[2], a1[2];
  #pragma unroll
  for (int q = 0; q < 2; q++) {
    int idx = tid + TMAIN*q;                 // float4 index, < 1024
    a0[q] = u0[idx]; a1[q] = u1[idx];
    z[ZS(4*idx+0)] = make_float2(a0[q].x, a1[q].x);
    z[ZS(4*idx+1)] = make_float2(a0[q].y, a1[q].y);
    z[ZS(4*idx+2)] = make_float2(a0[q].z, a1[q].z);
    z[ZS(4*idx+3)] = make_float2(a0[q].w, a1[q].w);
  }
  for (int i = tid + LSEQ; i < MFFT; i += TMAIN) z[ZS(i)] = make_float2(0.f, 0.f);
  __syncthreads();
  fft_fwd<TMAIN>(z, twl, ctl, tid);
  #pragma unroll
  for (int p0 = 0; p0 < MFFT; p0 += TMAIN) {
    int p = p0 + tid;                        // physical order on both sides
    z[p] = cmulf(z[p], Kd[p]);
  }
  __syncthreads();
  fft_inv<TMAIN>(z, twl, ctl, tid);
  const float Dv = Dp[0];
  float* o0 = out + (size_t)r0*LSEQ;
  float* o1 = out + (size_t)r1*LSEQ;
  #pragma unroll
  for (int q = 0; q < 2; q++) {
    int idx = tid + TMAIN*q;
    float2 w0 = z[ZS(4*idx+0)], w1 = z[ZS(4*idx+1)], w2 = z[ZS(4*idx+2)], w3 = z[ZS(4*idx+3)];
    float4 y0, y1;
    y0.x = w0.x + Dv*a0[q].x;  y1.x = w0.y + Dv*a1[q].x;
    y0.y = w1.x + Dv*a0[q].y;  y1.y = w1.y + Dv*a1[q].y;
    y0.z = w2.x + Dv*a0[q].z;  y1.z = w2.y + Dv*a1[q].z;
    y0.w = w3.x + Dv*a0[q].w;  y1.w = w3.y + Dv*a1[q].w;
    ((float4*)o0)[idx] = y0;
    ((float4*)o1)[idx] = y1;
  }
}

extern "C" void kernel_launch(void* const* d_in, const int* in_sizes, int n_in,
                              void* d_out, int out_size, void* d_ws, size_t ws_size,
                              hipStream_t stream) {
  const float* u     = (const float*)d_in[0];
  const float* Lre   = (const float*)d_in[1];
  const float* Lim   = (const float*)d_in[2];
  const float* Pre   = (const float*)d_in[3];
  const float* Pim   = (const float*)d_in[4];
  const float* Bre   = (const float*)d_in[5];
  const float* Bim   = (const float*)d_in[6];
  const float* Cri   = (const float*)d_in[7];
  const float* Dp    = (const float*)d_in[8];
  const float* lstep = (const float*)d_in[9];
  float* out = (float*)d_out;

  char* ws = (char*)d_ws;
  float2* a_ws    = (float2*)(ws);                  //  32768 B : at_roots
  float*  K_ws    = (float*)(ws + 32768);           //  16384 B : K time domain
  float2* Kd_ws   = (float2*)(ws + 49152);          //  65536 B : Kd (physical order, /M)
  float2* twq_ws  = (float2*)(ws + 114688);         //   8704 B : quarter twiddles
  float2* ctab_ws = (float2*)(ws + 123392);         //   5456 B : compact stage tables

  hipLaunchKernelGGL(tables_kernel, dim3(7),    dim3(256), 0, stream, twq_ws, ctab_ws);
  hipLaunchKernelGGL(cauchy_kernel, dim3(64),   dim3(64),  0, stream,
                     Lre, Lim, Pre, Pim, Bre, Bim, Cri, lstep, a_ws);
  hipLaunchKernelGGL(ktime_kernel,  dim3(1024), dim3(256), 0, stream, a_ws, K_ws);
  hipLaunchKernelGGL(kd_kernel,     dim3(1),    dim3(TMAIN), 0, stream,
                     K_ws, twq_ws, ctab_ws, Kd_ws);
  hipLaunchKernelGGL(conv_kernel,   dim3(NBH/2), dim3(TMAIN), 0, stream,
                     u, Dp, twq_ws, ctab_ws, Kd_ws, out);
}